// Round 4
// baseline (215.169 us; speedup 1.0000x reference)
//
#include <hip/hip_runtime.h>

// loss = sum_i ( -2*logits[i, t_i] + top1_i + top2_i )
// (log_softmax's lse cancels exactly: -2(x_t - lse) + (m1 - lse) + (m2 - lse)
//  = m1 + m2 - 2 x_t, since CONTRASTIVE_NUM == 2 == broadcast count)
// Harness delivers integer inputs as int32.
//
// R4: R2 structure (block-per-row, plain float4 loads) + fused reduction via
// one atomicAdd per block. NO nontemporal loads (R3 regression suspect).

#define NROWS 8192
#define VOCAB 32000

__global__ __launch_bounds__(256) void cce_kernel(const float* __restrict__ logits,
                                                  const int* __restrict__ target,
                                                  float* __restrict__ out) {
    const int row = blockIdx.x;
    const float4* rp = reinterpret_cast<const float4*>(logits + (size_t)row * VOCAB);

    // Issue the target gather early (thread 0); latency hides under the stream.
    float tv = 0.0f;
    if (threadIdx.x == 0) {
        const int t = target[row];
        tv = logits[(size_t)row * VOCAB + (size_t)t];
    }

    float m1 = -INFINITY, m2 = -INFINITY;
    for (int i = threadIdx.x; i < VOCAB / 4; i += 256) {
        float4 v = rp[i];
        m2 = fmaxf(m2, fminf(m1, v.x)); m1 = fmaxf(m1, v.x);
        m2 = fmaxf(m2, fminf(m1, v.y)); m1 = fmaxf(m1, v.y);
        m2 = fmaxf(m2, fminf(m1, v.z)); m1 = fmaxf(m1, v.z);
        m2 = fmaxf(m2, fminf(m1, v.w)); m1 = fmaxf(m1, v.w);
    }

    // 64-lane butterfly reduction of the (m1, m2) pair
    #pragma unroll
    for (int off = 32; off > 0; off >>= 1) {
        float o1 = __shfl_xor(m1, off, 64);
        float o2 = __shfl_xor(m2, off, 64);
        float nm1 = fmaxf(m1, o1);
        float nm2 = fmaxf(fminf(m1, o1), fmaxf(m2, o2));
        m1 = nm1; m2 = nm2;
    }

    __shared__ float s1[4], s2[4];
    const int wave = threadIdx.x >> 6;
    const int lane = threadIdx.x & 63;
    if (lane == 0) { s1[wave] = m1; s2[wave] = m2; }
    __syncthreads();

    if (threadIdx.x == 0) {
        m1 = s1[0]; m2 = s2[0];
        #pragma unroll
        for (int w = 1; w < 4; ++w) {
            float o1 = s1[w], o2 = s2[w];
            float nm1 = fmaxf(m1, o1);
            float nm2 = fmaxf(fminf(m1, o1), fmaxf(m2, o2));
            m1 = nm1; m2 = nm2;
        }
        atomicAdd(out, m1 + m2 - 2.0f * tv);   // one atomic per block, time-spread
    }
}

extern "C" void kernel_launch(void* const* d_in, const int* in_sizes, int n_in,
                              void* d_out, int out_size, void* d_ws, size_t ws_size,
                              hipStream_t stream) {
    const float* logits = (const float*)d_in[0];
    const int* target = (const int*)d_in[1];
    float* out = (float*)d_out;

    // Atomics accumulate into d_out: zero it every call (graph-safe memset node).
    hipMemsetAsync(out, 0, sizeof(float), stream);
    cce_kernel<<<NROWS, 256, 0, stream>>>(logits, target, out);
}

// Round 5
// 181.738 us; speedup vs baseline: 1.1840x; 1.1840x over previous
//
#include <hip/hip_runtime.h>

// loss = sum_i ( -2*logits[i, t_i] + top1_i + top2_i )
// (log_softmax's lse cancels exactly: -2(x_t - lse) + (m1 - lse) + (m2 - lse)
//  = m1 + m2 - 2 x_t, since CONTRASTIVE_NUM == 2 == broadcast count)
// Harness delivers integer inputs as int32.
//
// R5: R2 two-kernel structure; single variable changed = 1024-thread blocks
// (2 blocks/CU co-resident -> 512 concurrent HBM streams instead of 2048,
//  probing DRAM row-buffer-conflict theory for the 5.5 vs 6.3 TB/s gap).

#define NROWS 8192
#define VOCAB 32000
#define TPB 1024
#define NWAVES (TPB / 64)

__global__ __launch_bounds__(TPB) void cce_row_kernel(const float* __restrict__ logits,
                                                      const int* __restrict__ target,
                                                      float* __restrict__ row_partial) {
    const int row = blockIdx.x;
    const float4* rp = reinterpret_cast<const float4*>(logits + (size_t)row * VOCAB);

    // Issue the target gather early (thread 0); latency hides under the stream.
    float tv = 0.0f;
    if (threadIdx.x == 0) {
        const int t = target[row];
        tv = logits[(size_t)row * VOCAB + (size_t)t];
    }

    // 8000 float4 per row / 1024 threads: 7-8 iterations per thread.
    float m1 = -INFINITY, m2 = -INFINITY;
    for (int i = threadIdx.x; i < VOCAB / 4; i += TPB) {
        float4 v = rp[i];
        m2 = fmaxf(m2, fminf(m1, v.x)); m1 = fmaxf(m1, v.x);
        m2 = fmaxf(m2, fminf(m1, v.y)); m1 = fmaxf(m1, v.y);
        m2 = fmaxf(m2, fminf(m1, v.z)); m1 = fmaxf(m1, v.z);
        m2 = fmaxf(m2, fminf(m1, v.w)); m1 = fmaxf(m1, v.w);
    }

    // 64-lane butterfly reduction of the (m1, m2) pair
    #pragma unroll
    for (int off = 32; off > 0; off >>= 1) {
        float o1 = __shfl_xor(m1, off, 64);
        float o2 = __shfl_xor(m2, off, 64);
        float nm1 = fmaxf(m1, o1);
        float nm2 = fmaxf(fminf(m1, o1), fmaxf(m2, o2));
        m1 = nm1; m2 = nm2;
    }

    __shared__ float s1[NWAVES], s2[NWAVES];
    const int wave = threadIdx.x >> 6;
    const int lane = threadIdx.x & 63;
    if (lane == 0) { s1[wave] = m1; s2[wave] = m2; }
    __syncthreads();

    if (threadIdx.x == 0) {
        m1 = s1[0]; m2 = s2[0];
        #pragma unroll
        for (int w = 1; w < NWAVES; ++w) {
            float o1 = s1[w], o2 = s2[w];
            float nm1 = fmaxf(m1, o1);
            float nm2 = fmaxf(fminf(m1, o1), fmaxf(m2, o2));
            m1 = nm1; m2 = nm2;
        }
        row_partial[row] = m1 + m2 - 2.0f * tv;
    }
}

__global__ __launch_bounds__(256) void cce_reduce_kernel(const float* __restrict__ row_partial,
                                                         float* __restrict__ out) {
    float s = 0.0f;
    for (int i = threadIdx.x; i < NROWS; i += 256) s += row_partial[i];
    #pragma unroll
    for (int off = 32; off > 0; off >>= 1) s += __shfl_xor(s, off, 64);

    __shared__ float ws[4];
    const int wave = threadIdx.x >> 6;
    const int lane = threadIdx.x & 63;
    if (lane == 0) ws[wave] = s;
    __syncthreads();
    if (threadIdx.x == 0) out[0] = ws[0] + ws[1] + ws[2] + ws[3];
}

extern "C" void kernel_launch(void* const* d_in, const int* in_sizes, int n_in,
                              void* d_out, int out_size, void* d_ws, size_t ws_size,
                              hipStream_t stream) {
    const float* logits = (const float*)d_in[0];
    const int* target = (const int*)d_in[1];
    float* out = (float*)d_out;
    float* row_partial = (float*)d_ws;  // NROWS floats = 32 KiB

    cce_row_kernel<<<NROWS, TPB, 0, stream>>>(logits, target, row_partial);
    cce_reduce_kernel<<<1, 256, 0, stream>>>(row_partial, out);
}